// Round 3
// baseline (738.747 us; speedup 1.0000x reference)
//
#include <hip/hip_runtime.h>
#include <hip/hip_bf16.h>
#include <math.h>

#define B_SZ 128
#define I_DIM 512
#define H_DIM 1024
#define O_DIM 32
#define G4 4096
#define NSTEP 5

using short8 = __attribute__((ext_vector_type(8))) short;
using f32x4  = __attribute__((ext_vector_type(4))) float;

__device__ inline unsigned short f2bf(float f) {
    unsigned int u = __float_as_uint(f);
    unsigned int r = (u + 0x7fffu + ((u >> 16) & 1u)) >> 16;
    return (unsigned short)r;
}
__device__ inline float bf2f(unsigned short h) {
    return __uint_as_float(((unsigned int)h) << 16);
}

#define MFMA3(ACC, AH, AL, BH, BL)                                          \
    ACC = __builtin_amdgcn_mfma_f32_16x16x32_bf16(AH, BH, ACC, 0, 0, 0);    \
    ACC = __builtin_amdgcn_mfma_f32_16x16x32_bf16(AH, BL, ACC, 0, 0, 0);    \
    ACC = __builtin_amdgcn_mfma_f32_16x16x32_bf16(AL, BH, ACC, 0, 0, 0);

// ---------- per-call prep: zero state + bias sums ----------
__global__ __launch_bounds__(256) void init_misc(
    float* __restrict__ c0, float* __restrict__ c1,
    unsigned short* __restrict__ h0hi, unsigned short* __restrict__ h0lo,
    unsigned short* __restrict__ h1hi, unsigned short* __restrict__ h1lo,
    const float* __restrict__ bih0, const float* __restrict__ bhh0,
    const float* __restrict__ bih1, const float* __restrict__ bhh1,
    float* __restrict__ bsum0, float* __restrict__ bsum1)
{
    int i = blockIdx.x * 256 + threadIdx.x;
    if (i < B_SZ * H_DIM) {
        c0[i] = 0.f; c1[i] = 0.f;
        h0hi[i] = 0; h0lo[i] = 0; h1hi[i] = 0; h1lo[i] = 0;
    }
    if (i < G4) {
        bsum0[i] = bih0[i] + bhh0[i];
        bsum1[i] = bih1[i] + bhh1[i];
    }
}

// ---------- split fp32 -> bf16 hi/lo planes (4 weights + 5 input steps) ----------
__global__ __launch_bounds__(256) void conv_split(
    const float* __restrict__ s0, const float* __restrict__ s1,
    const float* __restrict__ s2, const float* __restrict__ s3,
    const float* __restrict__ s4,
    unsigned short* __restrict__ h0, unsigned short* __restrict__ l0,
    unsigned short* __restrict__ h1, unsigned short* __restrict__ l1,
    unsigned short* __restrict__ h2, unsigned short* __restrict__ l2,
    unsigned short* __restrict__ h3, unsigned short* __restrict__ l3,
    unsigned short* __restrict__ h4, unsigned short* __restrict__ l4)
{
    const long long E0 = 2097152;            // 4096*512
    const long long E1 = E0 + 4194304;       // + 4096*1024
    const long long E2 = E1 + 4194304;
    const long long E3 = E2 + 4194304;
    const long long E4 = E3 + 327680;        // + 640*512
    long long i4 = ((long long)blockIdx.x * 256 + threadIdx.x) * 4;
    if (i4 >= E4) return;
    const float* s; unsigned short *hh, *ll; long long base;
    if      (i4 < E0) { s = s0; hh = h0; ll = l0; base = 0;  }
    else if (i4 < E1) { s = s1; hh = h1; ll = l1; base = E0; }
    else if (i4 < E2) { s = s2; hh = h2; ll = l2; base = E1; }
    else if (i4 < E3) { s = s3; hh = h3; ll = l3; base = E2; }
    else              { s = s4; hh = h4; ll = l4; base = E3; }
    long long k = i4 - base;
    float4 v = *(const float4*)(s + k);
    ushort4 hv, lv;
    hv.x = f2bf(v.x); lv.x = f2bf(v.x - bf2f(hv.x));
    hv.y = f2bf(v.y); lv.y = f2bf(v.y - bf2f(hv.y));
    hv.z = f2bf(v.z); lv.z = f2bf(v.z - bf2f(hv.z));
    hv.w = f2bf(v.w); lv.w = f2bf(v.w - bf2f(hv.w));
    *(ushort4*)(hh + k) = hv;
    *(ushort4*)(ll + k) = lv;
}

// ---------- input GEMM: xg[640,4096] = X[640,512] @ Wih0^T + bsum0 ----------
// NT, split-bf16 MFMA, no LDS. 64x64 tile, 4 waves each 32x32.
__global__ __launch_bounds__(256) void gemm_in(
    const unsigned short* __restrict__ xhi, const unsigned short* __restrict__ xlo,
    const unsigned short* __restrict__ whi, const unsigned short* __restrict__ wlo,
    const float* __restrict__ bsum, float* __restrict__ xg)
{
    const int tid = threadIdx.x, lane = tid & 63, wv = tid >> 6;
    const int r = lane & 15, g = lane >> 4;
    const int wm = (wv & 1) * 32, wn = (wv >> 1) * 32;
    const int bm = blockIdx.y * 64, bn = blockIdx.x * 64;
    f32x4 acc[2][2];
    const f32x4 z = {0.f, 0.f, 0.f, 0.f};
    acc[0][0] = z; acc[0][1] = z; acc[1][0] = z; acc[1][1] = z;

    const unsigned short* Ah = xhi + (bm + wm + r) * I_DIM + g * 8;
    const unsigned short* Al = xlo + (bm + wm + r) * I_DIM + g * 8;
    const unsigned short* Bh = whi + (bn + wn + r) * I_DIM + g * 8;
    const unsigned short* Bl = wlo + (bn + wn + r) * I_DIM + g * 8;

    #pragma unroll 4
    for (int k = 0; k < I_DIM; k += 32) {
        short8 a0h = *(const short8*)(Ah + k);
        short8 a0l = *(const short8*)(Al + k);
        short8 a1h = *(const short8*)(Ah + 16 * I_DIM + k);
        short8 a1l = *(const short8*)(Al + 16 * I_DIM + k);
        short8 b0h = *(const short8*)(Bh + k);
        short8 b0l = *(const short8*)(Bl + k);
        short8 b1h = *(const short8*)(Bh + 16 * I_DIM + k);
        short8 b1l = *(const short8*)(Bl + 16 * I_DIM + k);
        MFMA3(acc[0][0], a0h, a0l, b0h, b0l);
        MFMA3(acc[0][1], a0h, a0l, b1h, b1l);
        MFMA3(acc[1][0], a1h, a1l, b0h, b0l);
        MFMA3(acc[1][1], a1h, a1l, b1h, b1l);
    }
    #pragma unroll
    for (int mf = 0; mf < 2; ++mf)
        #pragma unroll
        for (int nf = 0; nf < 2; ++nf)
            #pragma unroll
            for (int j = 0; j < 4; ++j) {
                int row = bm + wm + mf * 16 + g * 4 + j;
                int col = bn + wn + nf * 16 + r;
                xg[row * G4 + col] = acc[mf][nf][j] + bsum[col];
            }
}

// ---------- fused LSTM step: gemm (split-bf16 MFMA) + gates + h/c update ----------
// Block: 128 batch x 8 j-cols x 4 gates (32 gemm cols). Grid 128 blocks. 4 waves, each 32x32.
// LAYER==1 adds second pass (h1 @ whh1^T).
template<int LAYER>
__global__ __launch_bounds__(256) void lstm_step(
    const unsigned short* __restrict__ a1hi, const unsigned short* __restrict__ a1lo,
    const unsigned short* __restrict__ w1hi, const unsigned short* __restrict__ w1lo,
    const unsigned short* __restrict__ a2hi, const unsigned short* __restrict__ a2lo,
    const unsigned short* __restrict__ w2hi, const unsigned short* __restrict__ w2lo,
    const float* __restrict__ extra,   // LAYER0: xg_t[128][4096]; LAYER1: bsum1[4096]
    float* __restrict__ cst,
    unsigned short* __restrict__ hohi, unsigned short* __restrict__ holo)
{
    const int tid = threadIdx.x, lane = tid & 63, wv = tid >> 6;
    const int r = lane & 15, g = lane >> 4;
    const int jb0 = blockIdx.x * 8;
    const int wrow = wv * 32;
    // gemm col c -> gate q = c>>3, j = jb0 + (c&7); B row = q*H + j
    const int c0 = r, c1 = 16 + r;
    const int brow0 = (c0 >> 3) * H_DIM + jb0 + (c0 & 7);
    const int brow1 = (c1 >> 3) * H_DIM + jb0 + (c1 & 7);

    f32x4 acc[2][2];
    const f32x4 z = {0.f, 0.f, 0.f, 0.f};
    acc[0][0] = z; acc[0][1] = z; acc[1][0] = z; acc[1][1] = z;

    {
        const unsigned short* Ah = a1hi + (wrow + r) * H_DIM + g * 8;
        const unsigned short* Al = a1lo + (wrow + r) * H_DIM + g * 8;
        const unsigned short* B0h = w1hi + brow0 * H_DIM + g * 8;
        const unsigned short* B0l = w1lo + brow0 * H_DIM + g * 8;
        const unsigned short* B1h = w1hi + brow1 * H_DIM + g * 8;
        const unsigned short* B1l = w1lo + brow1 * H_DIM + g * 8;
        #pragma unroll 4
        for (int k = 0; k < H_DIM; k += 32) {
            short8 a0h = *(const short8*)(Ah + k);
            short8 a0l = *(const short8*)(Al + k);
            short8 a1h = *(const short8*)(Ah + 16 * H_DIM + k);
            short8 a1l = *(const short8*)(Al + 16 * H_DIM + k);
            short8 b0h = *(const short8*)(B0h + k);
            short8 b0l = *(const short8*)(B0l + k);
            short8 b1h = *(const short8*)(B1h + k);
            short8 b1l = *(const short8*)(B1l + k);
            MFMA3(acc[0][0], a0h, a0l, b0h, b0l);
            MFMA3(acc[0][1], a0h, a0l, b1h, b1l);
            MFMA3(acc[1][0], a1h, a1l, b0h, b0l);
            MFMA3(acc[1][1], a1h, a1l, b1h, b1l);
        }
    }
    if (LAYER == 1) {
        const unsigned short* Ah = a2hi + (wrow + r) * H_DIM + g * 8;
        const unsigned short* Al = a2lo + (wrow + r) * H_DIM + g * 8;
        const unsigned short* B0h = w2hi + brow0 * H_DIM + g * 8;
        const unsigned short* B0l = w2lo + brow0 * H_DIM + g * 8;
        const unsigned short* B1h = w2hi + brow1 * H_DIM + g * 8;
        const unsigned short* B1l = w2lo + brow1 * H_DIM + g * 8;
        #pragma unroll 4
        for (int k = 0; k < H_DIM; k += 32) {
            short8 a0h = *(const short8*)(Ah + k);
            short8 a0l = *(const short8*)(Al + k);
            short8 a1h = *(const short8*)(Ah + 16 * H_DIM + k);
            short8 a1l = *(const short8*)(Al + 16 * H_DIM + k);
            short8 b0h = *(const short8*)(B0h + k);
            short8 b0l = *(const short8*)(B0l + k);
            short8 b1h = *(const short8*)(B1h + k);
            short8 b1l = *(const short8*)(B1l + k);
            MFMA3(acc[0][0], a0h, a0l, b0h, b0l);
            MFMA3(acc[0][1], a0h, a0l, b1h, b1l);
            MFMA3(acc[1][0], a1h, a1l, b0h, b0l);
            MFMA3(acc[1][1], a1h, a1l, b1h, b1l);
        }
    }

    // epilogue: gather i/f/g/o and update c,h
    #pragma unroll
    for (int mf = 0; mf < 2; ++mf)
        #pragma unroll
        for (int j = 0; j < 4; ++j) {
            int b = wrow + mf * 16 + g * 4 + j;
            float v0 = acc[mf][0][j] + (LAYER == 0 ? extra[b * G4 + brow0] : extra[brow0]);
            float v1 = acc[mf][1][j] + (LAYER == 0 ? extra[b * G4 + brow1] : extra[brow1]);
            float u0 = __shfl_xor(v0, 8);   // col c^8: gate pair
            float u1 = __shfl_xor(v1, 8);
            if (r < 8) {
                // c0=jj (i), c0^8 (f), c1=16+jj (g), c1^8=24+jj (o)
                int jout = jb0 + r;
                int idx = b * H_DIM + jout;
                float ig = 1.f / (1.f + expf(-v0));
                float fg = 1.f / (1.f + expf(-u0));
                float gg = tanhf(v1);
                float og = 1.f / (1.f + expf(-u1));
                float cn = fg * cst[idx] + ig * gg;
                cst[idx] = cn;
                float h = og * tanhf(cn);
                unsigned short hh = f2bf(h);
                hohi[idx] = hh;
                holo[idx] = f2bf(h - bf2f(hh));
            }
        }
}

// ---------- head: out[b,o] = (h1hi+h1lo)[b,:] . w_out[o,:] + b_out[o] ----------
__global__ __launch_bounds__(64) void head_kernel(
    const unsigned short* __restrict__ hhi, const unsigned short* __restrict__ hlo,
    const float* __restrict__ w_out, const float* __restrict__ b_out,
    float* __restrict__ out)
{
    int o = blockIdx.x, b = blockIdx.y, lane = threadIdx.x;
    const unsigned short* hp = hhi + b * H_DIM;
    const unsigned short* lp = hlo + b * H_DIM;
    const float* wp = w_out + o * H_DIM;
    float s = 0.f;
    #pragma unroll
    for (int k = lane; k < H_DIM; k += 64)
        s += (bf2f(hp[k]) + bf2f(lp[k])) * wp[k];
    #pragma unroll
    for (int off = 32; off; off >>= 1) s += __shfl_down(s, off);
    if (lane == 0) out[b * O_DIM + o] = s + b_out[o];
}

extern "C" void kernel_launch(void* const* d_in, const int* in_sizes, int n_in,
                              void* d_out, int out_size, void* d_ws, size_t ws_size,
                              hipStream_t stream)
{
    const float* input   = (const float*)d_in[0];
    const float* w_ih_l0 = (const float*)d_in[1];
    const float* w_hh_l0 = (const float*)d_in[2];
    const float* b_ih_l0 = (const float*)d_in[3];
    const float* b_hh_l0 = (const float*)d_in[4];
    const float* w_ih_l1 = (const float*)d_in[5];
    const float* w_hh_l1 = (const float*)d_in[6];
    const float* b_ih_l1 = (const float*)d_in[7];
    const float* b_hh_l1 = (const float*)d_in[8];
    const float* w_out   = (const float*)d_in[9];
    const float* b_out   = (const float*)d_in[10];
    float* out = (float*)d_out;

    // ---- workspace layout (bytes) ----
    char* base = (char*)d_ws;
    size_t off = 0;
    auto alloc = [&](size_t bytes) { char* p = base + off; off = (off + bytes + 255) & ~(size_t)255; return p; };
    unsigned short* wih0_hi = (unsigned short*)alloc(2097152 * 2);
    unsigned short* wih0_lo = (unsigned short*)alloc(2097152 * 2);
    unsigned short* whh0_hi = (unsigned short*)alloc(4194304 * 2);
    unsigned short* whh0_lo = (unsigned short*)alloc(4194304 * 2);
    unsigned short* wih1_hi = (unsigned short*)alloc(4194304 * 2);
    unsigned short* wih1_lo = (unsigned short*)alloc(4194304 * 2);
    unsigned short* whh1_hi = (unsigned short*)alloc(4194304 * 2);
    unsigned short* whh1_lo = (unsigned short*)alloc(4194304 * 2);
    unsigned short* xhi     = (unsigned short*)alloc(327680 * 2);
    unsigned short* xlo     = (unsigned short*)alloc(327680 * 2);
    float* xg0   = (float*)alloc((size_t)NSTEP * B_SZ * G4 * 4);
    float* bsum0 = (float*)alloc(G4 * 4);
    float* bsum1 = (float*)alloc(G4 * 4);
    float* c0    = (float*)alloc(B_SZ * H_DIM * 4);
    float* c1    = (float*)alloc(B_SZ * H_DIM * 4);
    unsigned short* h0hi[2], *h0lo[2], *h1hi[2], *h1lo[2];
    for (int i = 0; i < 2; ++i) {
        h0hi[i] = (unsigned short*)alloc(B_SZ * H_DIM * 2);
        h0lo[i] = (unsigned short*)alloc(B_SZ * H_DIM * 2);
        h1hi[i] = (unsigned short*)alloc(B_SZ * H_DIM * 2);
        h1lo[i] = (unsigned short*)alloc(B_SZ * H_DIM * 2);
    }

    // ---- prep ----
    init_misc<<<(B_SZ * H_DIM + 255) / 256, 256, 0, stream>>>(
        c0, c1, h0hi[0], h0lo[0], h1hi[0], h1lo[0],
        b_ih_l0, b_hh_l0, b_ih_l1, b_hh_l1, bsum0, bsum1);

    conv_split<<<(15007744 / 4 + 255) / 256, 256, 0, stream>>>(
        w_ih_l0, w_hh_l0, w_ih_l1, w_hh_l1, input,
        wih0_hi, wih0_lo, whh0_hi, whh0_lo, wih1_hi, wih1_lo,
        whh1_hi, whh1_lo, xhi, xlo);

    // xg0 = X @ Wih0^T + (b_ih0+b_hh0)
    gemm_in<<<dim3(G4 / 64, (NSTEP * B_SZ) / 64), 256, 0, stream>>>(
        xhi, xlo, wih0_hi, wih0_lo, bsum0, xg0);

    // ---- 5 recurrent steps ----
    for (int t = 0; t < NSTEP; ++t) {
        int in = t & 1, o2 = 1 - in;
        lstm_step<0><<<H_DIM / 8, 256, 0, stream>>>(
            h0hi[in], h0lo[in], whh0_hi, whh0_lo,
            nullptr, nullptr, nullptr, nullptr,
            xg0 + (size_t)t * B_SZ * G4, c0, h0hi[o2], h0lo[o2]);
        lstm_step<1><<<H_DIM / 8, 256, 0, stream>>>(
            h0hi[o2], h0lo[o2], wih1_hi, wih1_lo,
            h1hi[in], h1lo[in], whh1_hi, whh1_lo,
            bsum1, c1, h1hi[o2], h1lo[o2]);
    }

    // final h1 lives in buffer index 1 (t=4: out = 1)
    head_kernel<<<dim3(O_DIM, B_SZ), 64, 0, stream>>>(
        h1hi[1], h1lo[1], w_out, b_out, out);
}

// Round 6
// 519.468 us; speedup vs baseline: 1.4221x; 1.4221x over previous
//
#include <hip/hip_runtime.h>
#include <hip/hip_bf16.h>
#include <math.h>

#define B_SZ 128
#define I_DIM 512
#define H_DIM 1024
#define O_DIM 32
#define G4 4096
#define NSTEP 5          // only h2[4] is consumed -> 5 timesteps

using short8 = __attribute__((ext_vector_type(8))) short;
using f32x4  = __attribute__((ext_vector_type(4))) float;

__device__ inline unsigned short f2bf(float f) {
    unsigned int u = __float_as_uint(f);
    return (unsigned short)((u + 0x7fffu + ((u >> 16) & 1u)) >> 16);
}
__device__ inline float bf2f(unsigned short h) {
    return __uint_as_float(((unsigned int)h) << 16);
}
__device__ inline float sigf(float x) { return 1.f / (1.f + expf(-x)); }

#define MFMA3(ACC, AH, AL, BH, BL)                                           \
    ACC = __builtin_amdgcn_mfma_f32_16x16x32_bf16(AH, BH, ACC, 0, 0, 0);     \
    ACC = __builtin_amdgcn_mfma_f32_16x16x32_bf16(AH, BL, ACC, 0, 0, 0);     \
    ACC = __builtin_amdgcn_mfma_f32_16x16x32_bf16(AL, BH, ACC, 0, 0, 0);

// ---------- prep: zero state + bias sums (validated round 3) ----------
__global__ __launch_bounds__(256) void init_misc(
    float* __restrict__ c0, float* __restrict__ c1,
    unsigned short* __restrict__ h0hi, unsigned short* __restrict__ h0lo,
    unsigned short* __restrict__ h1hi, unsigned short* __restrict__ h1lo,
    const float* __restrict__ bih0, const float* __restrict__ bhh0,
    const float* __restrict__ bih1, const float* __restrict__ bhh1,
    float* __restrict__ bsum0, float* __restrict__ bsum1)
{
    int i = blockIdx.x * 256 + threadIdx.x;
    if (i < B_SZ * H_DIM) {
        c0[i] = 0.f; c1[i] = 0.f;
        h0hi[i] = 0; h0lo[i] = 0; h1hi[i] = 0; h1lo[i] = 0;
    }
    if (i < G4) {
        bsum0[i] = bih0[i] + bhh0[i];
        bsum1[i] = bih1[i] + bhh1[i];
    }
}

// ---------- split fp32 -> bf16 hi/lo planes (validated round 3) ----------
__global__ __launch_bounds__(256) void conv_split(
    const float* __restrict__ s0, const float* __restrict__ s1,
    const float* __restrict__ s2, const float* __restrict__ s3,
    const float* __restrict__ s4,
    unsigned short* __restrict__ h0, unsigned short* __restrict__ l0,
    unsigned short* __restrict__ h1, unsigned short* __restrict__ l1,
    unsigned short* __restrict__ h2, unsigned short* __restrict__ l2,
    unsigned short* __restrict__ h3, unsigned short* __restrict__ l3,
    unsigned short* __restrict__ h4, unsigned short* __restrict__ l4)
{
    const long long E0 = 2097152;            // 4096*512
    const long long E1 = E0 + 4194304;       // + 4096*1024
    const long long E2 = E1 + 4194304;
    const long long E3 = E2 + 4194304;
    const long long E4 = E3 + 327680;        // + 640*512
    long long i4 = ((long long)blockIdx.x * 256 + threadIdx.x) * 4;
    if (i4 >= E4) return;
    const float* s; unsigned short *hh, *ll; long long base;
    if      (i4 < E0) { s = s0; hh = h0; ll = l0; base = 0;  }
    else if (i4 < E1) { s = s1; hh = h1; ll = l1; base = E0; }
    else if (i4 < E2) { s = s2; hh = h2; ll = l2; base = E1; }
    else if (i4 < E3) { s = s3; hh = h3; ll = l3; base = E2; }
    else              { s = s4; hh = h4; ll = l4; base = E3; }
    long long k = i4 - base;
    float4 v = *(const float4*)(s + k);
    ushort4 hv, lv;
    hv.x = f2bf(v.x); lv.x = f2bf(v.x - bf2f(hv.x));
    hv.y = f2bf(v.y); lv.y = f2bf(v.y - bf2f(hv.y));
    hv.z = f2bf(v.z); lv.z = f2bf(v.z - bf2f(hv.z));
    hv.w = f2bf(v.w); lv.w = f2bf(v.w - bf2f(hv.w));
    *(ushort4*)(hh + k) = hv;
    *(ushort4*)(ll + k) = lv;
}

// ---------- input GEMM (validated round 3): xg = X @ Wih0^T + bsum0 ----------
__global__ __launch_bounds__(256) void gemm_in(
    const unsigned short* __restrict__ xhi, const unsigned short* __restrict__ xlo,
    const unsigned short* __restrict__ whi, const unsigned short* __restrict__ wlo,
    const float* __restrict__ bsum, float* __restrict__ xg)
{
    const int tid = threadIdx.x, lane = tid & 63, wv = tid >> 6;
    const int r = lane & 15, g = lane >> 4;
    const int wm = (wv & 1) * 32, wn = (wv >> 1) * 32;
    const int bm = blockIdx.y * 64, bn = blockIdx.x * 64;
    f32x4 acc[2][2];
    const f32x4 z = {0.f, 0.f, 0.f, 0.f};
    acc[0][0] = z; acc[0][1] = z; acc[1][0] = z; acc[1][1] = z;

    const unsigned short* Ah = xhi + (bm + wm + r) * I_DIM + g * 8;
    const unsigned short* Al = xlo + (bm + wm + r) * I_DIM + g * 8;
    const unsigned short* Bh = whi + (bn + wn + r) * I_DIM + g * 8;
    const unsigned short* Bl = wlo + (bn + wn + r) * I_DIM + g * 8;

    #pragma unroll 4
    for (int k = 0; k < I_DIM; k += 32) {
        short8 a0h = *(const short8*)(Ah + k);
        short8 a0l = *(const short8*)(Al + k);
        short8 a1h = *(const short8*)(Ah + 16 * I_DIM + k);
        short8 a1l = *(const short8*)(Al + 16 * I_DIM + k);
        short8 b0h = *(const short8*)(Bh + k);
        short8 b0l = *(const short8*)(Bl + k);
        short8 b1h = *(const short8*)(Bh + 16 * I_DIM + k);
        short8 b1l = *(const short8*)(Bl + 16 * I_DIM + k);
        MFMA3(acc[0][0], a0h, a0l, b0h, b0l);
        MFMA3(acc[0][1], a0h, a0l, b1h, b1l);
        MFMA3(acc[1][0], a1h, a1l, b0h, b0l);
        MFMA3(acc[1][1], a1h, a1l, b1h, b1l);
    }
    #pragma unroll
    for (int mf = 0; mf < 2; ++mf)
        #pragma unroll
        for (int nf = 0; nf < 2; ++nf)
            #pragma unroll
            for (int j = 0; j < 4; ++j) {
                int row = bm + wm + mf * 16 + g * 4 + j;
                int col = bn + wn + nf * 16 + r;
                xg[row * G4 + col] = acc[mf][nf][j] + bsum[col];
            }
}

// ---------- LSTM step, high-occupancy: 256 blocks x 512 threads (8 waves) ----
// Block owns j in [4*bid,4*bid+4) x 4 gates = 16 MFMA cols; waves K-split.
// L0: waves cover K=1024 in chunks of 128 (A=h0_in, W=whh0); extra = xg_t
//     (bias already in xg). L1: waves 0-3 cover wih1 (A=h0_new), waves 4-7
//     whh1 (A=h1_in), 256-chunks; extra = bsum1. LDS reduce across waves,
//     fused sigmoid/tanh gate math, c (fp32, global, in-place), h planes
//     ping-ponged across dispatches.
template<int LAYER>
__global__ __launch_bounds__(512) void lstm_step(
    const unsigned short* __restrict__ a1hi, const unsigned short* __restrict__ a1lo,
    const unsigned short* __restrict__ w1hi, const unsigned short* __restrict__ w1lo,
    const unsigned short* __restrict__ a2hi, const unsigned short* __restrict__ a2lo,
    const unsigned short* __restrict__ w2hi, const unsigned short* __restrict__ w2lo,
    const float* __restrict__ extra,
    float* __restrict__ cst,
    unsigned short* __restrict__ hohi, unsigned short* __restrict__ holo)
{
    __shared__ float lds_p[8][B_SZ][17];
    const int tid = threadIdx.x, lane = tid & 63, wv = tid >> 6;
    const int r = lane & 15, g = lane >> 4;
    const int jb = blockIdx.x * 4;
    const int q = r >> 2, j4 = r & 3;
    const int wrow = q * H_DIM + jb + j4;        // weight row for col r

    f32x4 acc[8];
    const f32x4 z = {0.f, 0.f, 0.f, 0.f};
    #pragma unroll
    for (int mf = 0; mf < 8; ++mf) acc[mf] = z;

    if (LAYER == 0) {
        const int kb = wv * 128;
        const unsigned short* Wh = w1hi + (long long)wrow * H_DIM + kb + g * 8;
        const unsigned short* Wl = w1lo + (long long)wrow * H_DIM + kb + g * 8;
        const unsigned short* Ah = a1hi + kb + g * 8;
        const unsigned short* Al = a1lo + kb + g * 8;
        #pragma unroll
        for (int ks = 0; ks < 4; ++ks) {
            short8 bh = *(const short8*)(Wh + ks * 32);
            short8 bl = *(const short8*)(Wl + ks * 32);
            #pragma unroll
            for (int mf = 0; mf < 8; ++mf) {
                int off = (mf * 16 + r) * H_DIM + ks * 32;
                short8 ah = *(const short8*)(Ah + off);
                short8 al = *(const short8*)(Al + off);
                MFMA3(acc[mf], ah, al, bh, bl);
            }
        }
    } else {
        const int kb = (wv & 3) * 256;
        const unsigned short* Wsrc_h = (wv < 4) ? w1hi : w2hi;
        const unsigned short* Wsrc_l = (wv < 4) ? w1lo : w2lo;
        const unsigned short* Asrc_h = (wv < 4) ? a1hi : a2hi;
        const unsigned short* Asrc_l = (wv < 4) ? a1lo : a2lo;
        const unsigned short* Wh = Wsrc_h + (long long)wrow * H_DIM + kb + g * 8;
        const unsigned short* Wl = Wsrc_l + (long long)wrow * H_DIM + kb + g * 8;
        const unsigned short* Ah = Asrc_h + kb + g * 8;
        const unsigned short* Al = Asrc_l + kb + g * 8;
        #pragma unroll
        for (int ks = 0; ks < 8; ++ks) {
            short8 bh = *(const short8*)(Wh + ks * 32);
            short8 bl = *(const short8*)(Wl + ks * 32);
            #pragma unroll
            for (int mf = 0; mf < 8; ++mf) {
                int off = (mf * 16 + r) * H_DIM + ks * 32;
                short8 ah = *(const short8*)(Ah + off);
                short8 al = *(const short8*)(Al + off);
                MFMA3(acc[mf], ah, al, bh, bl);
            }
        }
    }

    // stash partials: C frag layout col=lane&15, row=(lane>>4)*4+j (m89)
    #pragma unroll
    for (int mf = 0; mf < 8; ++mf)
        #pragma unroll
        for (int j = 0; j < 4; ++j)
            lds_p[wv][mf * 16 + g * 4 + j][r] = acc[mf][j];
    __syncthreads();

    // reduce + gates: 512 threads = 128 batch x 4 j-cols
    {
        int b = tid & 127, jj = tid >> 7;
        float gs[4];
        #pragma unroll
        for (int qq = 0; qq < 4; ++qq) {
            int col = qq * 4 + jj;
            float s = 0.f;
            #pragma unroll
            for (int w = 0; w < 8; ++w) s += lds_p[w][b][col];
            s += (LAYER == 0) ? extra[b * G4 + qq * H_DIM + jb + jj]
                              : extra[qq * H_DIM + jb + jj];
            gs[qq] = s;
        }
        int idx = b * H_DIM + jb + jj;
        float cn = sigf(gs[1]) * cst[idx] + sigf(gs[0]) * tanhf(gs[2]);
        cst[idx] = cn;
        float h = sigf(gs[3]) * tanhf(cn);
        unsigned short hh = f2bf(h);
        hohi[idx] = hh;
        holo[idx] = f2bf(h - bf2f(hh));
    }
}

// ---------- head (validated round 3) ----------
__global__ __launch_bounds__(64) void head_kernel(
    const unsigned short* __restrict__ hhi, const unsigned short* __restrict__ hlo,
    const float* __restrict__ w_out, const float* __restrict__ b_out,
    float* __restrict__ out)
{
    int o = blockIdx.x, b = blockIdx.y, lane = threadIdx.x;
    const unsigned short* hp = hhi + b * H_DIM;
    const unsigned short* lp = hlo + b * H_DIM;
    const float* wp = w_out + o * H_DIM;
    float s = 0.f;
    #pragma unroll
    for (int k = lane; k < H_DIM; k += 64)
        s += (bf2f(hp[k]) + bf2f(lp[k])) * wp[k];
    #pragma unroll
    for (int off = 32; off; off >>= 1) s += __shfl_down(s, off);
    if (lane == 0) out[b * O_DIM + o] = s + b_out[o];
}

extern "C" void kernel_launch(void* const* d_in, const int* in_sizes, int n_in,
                              void* d_out, int out_size, void* d_ws, size_t ws_size,
                              hipStream_t stream)
{
    const float* input   = (const float*)d_in[0];
    const float* w_ih_l0 = (const float*)d_in[1];
    const float* w_hh_l0 = (const float*)d_in[2];
    const float* b_ih_l0 = (const float*)d_in[3];
    const float* b_hh_l0 = (const float*)d_in[4];
    const float* w_ih_l1 = (const float*)d_in[5];
    const float* w_hh_l1 = (const float*)d_in[6];
    const float* b_ih_l1 = (const float*)d_in[7];
    const float* b_hh_l1 = (const float*)d_in[8];
    const float* w_out   = (const float*)d_in[9];
    const float* b_out   = (const float*)d_in[10];
    float* out = (float*)d_out;

    char* base = (char*)d_ws;
    size_t off = 0;
    auto alloc = [&](size_t bytes) { char* p = base + off; off = (off + bytes + 255) & ~(size_t)255; return p; };
    unsigned short* wih0_hi = (unsigned short*)alloc(2097152 * 2);
    unsigned short* wih0_lo = (unsigned short*)alloc(2097152 * 2);
    unsigned short* whh0_hi = (unsigned short*)alloc(4194304 * 2);
    unsigned short* whh0_lo = (unsigned short*)alloc(4194304 * 2);
    unsigned short* wih1_hi = (unsigned short*)alloc(4194304 * 2);
    unsigned short* wih1_lo = (unsigned short*)alloc(4194304 * 2);
    unsigned short* whh1_hi = (unsigned short*)alloc(4194304 * 2);
    unsigned short* whh1_lo = (unsigned short*)alloc(4194304 * 2);
    unsigned short* xhi     = (unsigned short*)alloc(327680 * 2);
    unsigned short* xlo     = (unsigned short*)alloc(327680 * 2);
    float* xg0   = (float*)alloc((size_t)NSTEP * B_SZ * G4 * 4);
    float* bsum0 = (float*)alloc(G4 * 4);
    float* bsum1 = (float*)alloc(G4 * 4);
    float* c0    = (float*)alloc(B_SZ * H_DIM * 4);
    float* c1    = (float*)alloc(B_SZ * H_DIM * 4);
    unsigned short* h0hi[2], *h0lo[2], *h1hi[2], *h1lo[2];
    for (int i = 0; i < 2; ++i) {
        h0hi[i] = (unsigned short*)alloc(B_SZ * H_DIM * 2);
        h0lo[i] = (unsigned short*)alloc(B_SZ * H_DIM * 2);
        h1hi[i] = (unsigned short*)alloc(B_SZ * H_DIM * 2);
        h1lo[i] = (unsigned short*)alloc(B_SZ * H_DIM * 2);
    }

    init_misc<<<(B_SZ * H_DIM + 255) / 256, 256, 0, stream>>>(
        c0, c1, h0hi[0], h0lo[0], h1hi[0], h1lo[0],
        b_ih_l0, b_hh_l0, b_ih_l1, b_hh_l1, bsum0, bsum1);

    conv_split<<<(15007744 / 4 + 255) / 256, 256, 0, stream>>>(
        w_ih_l0, w_hh_l0, w_ih_l1, w_hh_l1, input,
        wih0_hi, wih0_lo, whh0_hi, whh0_lo, wih1_hi, wih1_lo,
        whh1_hi, whh1_lo, xhi, xlo);

    gemm_in<<<dim3(G4 / 64, (NSTEP * B_SZ) / 64), 256, 0, stream>>>(
        xhi, xlo, wih0_hi, wih0_lo, bsum0, xg0);

    for (int t = 0; t < NSTEP; ++t) {
        int in = t & 1, o2 = 1 - in;
        lstm_step<0><<<H_DIM / 4, 512, 0, stream>>>(
            h0hi[in], h0lo[in], whh0_hi, whh0_lo,
            nullptr, nullptr, nullptr, nullptr,
            xg0 + (size_t)t * B_SZ * G4, c0, h0hi[o2], h0lo[o2]);
        lstm_step<1><<<H_DIM / 4, 512, 0, stream>>>(
            h0hi[o2], h0lo[o2], wih1_hi, wih1_lo,
            h1hi[in], h1lo[in], whh1_hi, whh1_lo,
            bsum1, c1, h1hi[o2], h1lo[o2]);
    }

    // t=4: out parity = 1
    head_kernel<<<dim3(O_DIM, B_SZ), 64, 0, stream>>>(
        h1hi[1], h1lo[1], w_out, b_out, out);
}

// Round 8
// 417.463 us; speedup vs baseline: 1.7696x; 1.2443x over previous
//
#include <hip/hip_runtime.h>
#include <hip/hip_bf16.h>
#include <math.h>

#define B_SZ 128
#define I_DIM 512
#define H_DIM 1024
#define O_DIM 32
#define G4 4096
#define NSTEP 5          // only h2[4] is consumed -> 5 timesteps

using short8 = __attribute__((ext_vector_type(8))) short;
using f32x4  = __attribute__((ext_vector_type(4))) float;

__device__ inline unsigned short f2bf(float f) {
    unsigned int u = __float_as_uint(f);
    return (unsigned short)((u + 0x7fffu + ((u >> 16) & 1u)) >> 16);
}
__device__ inline float bf2f(unsigned short h) {
    return __uint_as_float(((unsigned int)h) << 16);
}
__device__ inline float sigf(float x) { return 1.f / (1.f + expf(-x)); }

#define MFMA3(ACC, AH, AL, BH, BL)                                           \
    ACC = __builtin_amdgcn_mfma_f32_16x16x32_bf16(AH, BH, ACC, 0, 0, 0);     \
    ACC = __builtin_amdgcn_mfma_f32_16x16x32_bf16(AH, BL, ACC, 0, 0, 0);     \
    ACC = __builtin_amdgcn_mfma_f32_16x16x32_bf16(AL, BH, ACC, 0, 0, 0);

// ================= PK (fragment-packed) layout =================
// Tile = 16 rows x 32 k. lane l = g*16+r owns row r, k-sub g*8..g*8+8 (16B).
// ushort idx = ((rt*NKT + kt)*64 + g*16 + r)*8 + (k&7).
// Weights (whh0/wih1/whh1) packed PER CONSUMER BLOCK: block bid owns wrows
// {q*1024 + bid*4 + j4}, fragment col r = q*4+j4 -> bid replaces rt (NKT=32).

// ---------- prep: zero state + bias sums ----------
__global__ __launch_bounds__(256) void init_misc(
    float* __restrict__ c0, float* __restrict__ c1,
    unsigned short* __restrict__ h0hi, unsigned short* __restrict__ h0lo,
    unsigned short* __restrict__ h1hi, unsigned short* __restrict__ h1lo,
    const float* __restrict__ bih0, const float* __restrict__ bhh0,
    const float* __restrict__ bih1, const float* __restrict__ bhh1,
    float* __restrict__ bsum0, float* __restrict__ bsum1)
{
    int i = blockIdx.x * 256 + threadIdx.x;
    if (i < B_SZ * H_DIM) {
        c0[i] = 0.f; c1[i] = 0.f;
        h0hi[i] = 0; h0lo[i] = 0; h1hi[i] = 0; h1lo[i] = 0;
    }
    if (i < G4) {
        bsum0[i] = bih0[i] + bhh0[i];
        bsum1[i] = bih1[i] + bhh1[i];
    }
}

// ---------- split fp32 -> bf16 hi/lo planes, PACKED layouts ----------
__global__ __launch_bounds__(256) void conv_pack(
    const float* __restrict__ s_wih0, const float* __restrict__ s_whh0,
    const float* __restrict__ s_wih1, const float* __restrict__ s_whh1,
    const float* __restrict__ s_x,
    unsigned short* __restrict__ d_wih0h, unsigned short* __restrict__ d_wih0l,
    unsigned short* __restrict__ d_whh0h, unsigned short* __restrict__ d_whh0l,
    unsigned short* __restrict__ d_wih1h, unsigned short* __restrict__ d_wih1l,
    unsigned short* __restrict__ d_whh1h, unsigned short* __restrict__ d_whh1l,
    unsigned short* __restrict__ d_xh,   unsigned short* __restrict__ d_xl)
{
    // group = 8 consecutive k of one row
    const long long G0 = 262144;             // wih0: 4096*512/8
    const long long G1 = G0 + 524288;        // whh0: 4096*1024/8
    const long long G2 = G1 + 524288;        // wih1
    const long long G3 = G2 + 524288;        // whh1
    const long long GT = G3 + 40960;         // x: 640*512/8
    long long i8 = (long long)blockIdx.x * 256 + threadIdx.x;
    if (i8 >= GT) return;
    const float* src; unsigned short *dh, *dl;
    int row, k8, K, blockpk;
    if (i8 < G0)      { long long lg = i8;      src = s_wih0; dh = d_wih0h; dl = d_wih0l; K = 512;  blockpk = 0; row = (int)(lg >> 6);  k8 = (int)(lg & 63);  }
    else if (i8 < G1) { long long lg = i8 - G0; src = s_whh0; dh = d_whh0h; dl = d_whh0l; K = 1024; blockpk = 1; row = (int)(lg >> 7);  k8 = (int)(lg & 127); }
    else if (i8 < G2) { long long lg = i8 - G1; src = s_wih1; dh = d_wih1h; dl = d_wih1l; K = 1024; blockpk = 1; row = (int)(lg >> 7);  k8 = (int)(lg & 127); }
    else if (i8 < G3) { long long lg = i8 - G2; src = s_whh1; dh = d_whh1h; dl = d_whh1l; K = 1024; blockpk = 1; row = (int)(lg >> 7);  k8 = (int)(lg & 127); }
    else              { long long lg = i8 - G3; src = s_x;    dh = d_xh;    dl = d_xl;    K = 512;  blockpk = 0; row = (int)(lg >> 6);  k8 = (int)(lg & 63);  }
    int kt = k8 >> 2, g = k8 & 3;
    long long dst;
    if (blockpk) {
        int j = row & 1023, q = row >> 10;
        int r = q * 4 + (j & 3);
        dst = (((long long)(j >> 2) * 32 + kt) * 64 + g * 16 + r) * 8;
    } else {
        int NKT = K >> 5;                    // 16
        dst = (((long long)(row >> 4) * NKT + kt) * 64 + g * 16 + (row & 15)) * 8;
    }
    const float* p = src + (long long)row * K + k8 * 8;
    float4 a = *(const float4*)p;
    float4 b = *(const float4*)(p + 4);
    float v[8] = {a.x, a.y, a.z, a.w, b.x, b.y, b.z, b.w};
    short8 hv, lv;
    #pragma unroll
    for (int i = 0; i < 8; ++i) {
        unsigned short h = f2bf(v[i]);
        hv[i] = (short)h;
        lv[i] = (short)f2bf(v[i] - bf2f(h));
    }
    *(short8*)(dh + dst) = hv;
    *(short8*)(dl + dst) = lv;
}

// ---------- input GEMM: xg[640,4096] = X @ Wih0^T + bsum0 (PK operands) ----
__global__ __launch_bounds__(256) void gemm_in(
    const unsigned short* __restrict__ xh, const unsigned short* __restrict__ xl,
    const unsigned short* __restrict__ wh, const unsigned short* __restrict__ wl,
    const float* __restrict__ bsum, float* __restrict__ xg)
{
    const int tid = threadIdx.x, lane = tid & 63, wv = tid >> 6;
    const int r = lane & 15, g = lane >> 4;
    const int wm = (wv & 1) * 32, wn = (wv >> 1) * 32;
    const int bm = blockIdx.y * 64, bn = blockIdx.x * 64;
    const int art = (bm + wm) >> 4, brt = (bn + wn) >> 4;   // NKT=16, rt stride 8192 us
    f32x4 acc[2][2];
    const f32x4 z = {0.f, 0.f, 0.f, 0.f};
    acc[0][0] = z; acc[0][1] = z; acc[1][0] = z; acc[1][1] = z;

    const unsigned short* A0h = xh + (long long)art * 8192 + lane * 8;
    const unsigned short* A0l = xl + (long long)art * 8192 + lane * 8;
    const unsigned short* B0h = wh + (long long)brt * 8192 + lane * 8;
    const unsigned short* B0l = wl + (long long)brt * 8192 + lane * 8;

    #pragma unroll 4
    for (int kt = 0; kt < 16; ++kt) {
        int o = kt * 512;
        short8 a0h = *(const short8*)(A0h + o);
        short8 a0l = *(const short8*)(A0l + o);
        short8 a1h = *(const short8*)(A0h + 8192 + o);
        short8 a1l = *(const short8*)(A0l + 8192 + o);
        short8 b0h = *(const short8*)(B0h + o);
        short8 b0l = *(const short8*)(B0l + o);
        short8 b1h = *(const short8*)(B0h + 8192 + o);
        short8 b1l = *(const short8*)(B0l + 8192 + o);
        MFMA3(acc[0][0], a0h, a0l, b0h, b0l);
        MFMA3(acc[0][1], a0h, a0l, b1h, b1l);
        MFMA3(acc[1][0], a1h, a1l, b0h, b0l);
        MFMA3(acc[1][1], a1h, a1l, b1h, b1l);
    }
    #pragma unroll
    for (int mf = 0; mf < 2; ++mf)
        #pragma unroll
        for (int nf = 0; nf < 2; ++nf)
            #pragma unroll
            for (int j = 0; j < 4; ++j) {
                int row = bm + wm + mf * 16 + g * 4 + j;
                int col = bn + wn + nf * 16 + r;
                xg[(long long)row * G4 + col] = acc[mf][nf][j] + bsum[col];
            }
}

// ---------- LSTM step: 256 blocks x 512 threads (8 waves), PK operands ----
// Block bid owns j in [4*bid,4*bid+4) x 4 gates = 16 MFMA cols. Waves K-split.
// L0: wave wv covers kt wv*4..+4 (A=h0in, W=whh0pk); extra = xg_t row-major.
// L1: waves 0-3 wih1pk (A=h0new), waves 4-7 whh1pk (A=h1in), kt (wv&3)*8..+8;
//     extra = bsum1. LDS reduce, fused gates, cT[j][b] fp32, PK h output.
template<int LAYER>
__global__ __launch_bounds__(512) void lstm_step(
    const unsigned short* __restrict__ a1hi, const unsigned short* __restrict__ a1lo,
    const unsigned short* __restrict__ w1hi, const unsigned short* __restrict__ w1lo,
    const unsigned short* __restrict__ a2hi, const unsigned short* __restrict__ a2lo,
    const unsigned short* __restrict__ w2hi, const unsigned short* __restrict__ w2lo,
    const float* __restrict__ extra,
    float* __restrict__ cst,
    unsigned short* __restrict__ hohi, unsigned short* __restrict__ holo)
{
    __shared__ float lds_p[8][B_SZ][17];
    const int tid = threadIdx.x, lane = tid & 63, wv = tid >> 6;
    const int r = lane & 15, g = lane >> 4;
    const int jb = blockIdx.x * 4;

    f32x4 acc[8];
    const f32x4 z = {0.f, 0.f, 0.f, 0.f};
    #pragma unroll
    for (int mf = 0; mf < 8; ++mf) acc[mf] = z;

    if (LAYER == 0) {
        const unsigned short* Wh = w1hi + (long long)blockIdx.x * 16384 + lane * 8;
        const unsigned short* Wl = w1lo + (long long)blockIdx.x * 16384 + lane * 8;
        const unsigned short* Ah = a1hi + lane * 8;
        const unsigned short* Al = a1lo + lane * 8;
        const int kt0 = wv * 4;
        #pragma unroll
        for (int ks = 0; ks < 4; ++ks) {
            const int kt = kt0 + ks;
            short8 bh = *(const short8*)(Wh + kt * 512);
            short8 bl = *(const short8*)(Wl + kt * 512);
            #pragma unroll
            for (int mf = 0; mf < 8; ++mf) {
                long long o = ((long long)mf * 32 + kt) * 512;
                short8 ah = *(const short8*)(Ah + o);
                short8 al = *(const short8*)(Al + o);
                MFMA3(acc[mf], ah, al, bh, bl);
            }
        }
    } else {
        const unsigned short* Wh = ((wv < 4) ? w1hi : w2hi) + (long long)blockIdx.x * 16384 + lane * 8;
        const unsigned short* Wl = ((wv < 4) ? w1lo : w2lo) + (long long)blockIdx.x * 16384 + lane * 8;
        const unsigned short* Ah = ((wv < 4) ? a1hi : a2hi) + lane * 8;
        const unsigned short* Al = ((wv < 4) ? a1lo : a2lo) + lane * 8;
        const int kt0 = (wv & 3) * 8;
        #pragma unroll
        for (int ks = 0; ks < 8; ++ks) {
            const int kt = kt0 + ks;
            short8 bh = *(const short8*)(Wh + kt * 512);
            short8 bl = *(const short8*)(Wl + kt * 512);
            #pragma unroll
            for (int mf = 0; mf < 8; ++mf) {
                long long o = ((long long)mf * 32 + kt) * 512;
                short8 ah = *(const short8*)(Ah + o);
                short8 al = *(const short8*)(Al + o);
                MFMA3(acc[mf], ah, al, bh, bl);
            }
        }
    }

    // stash partials: C frag (m89) col=lane&15, row=(lane>>4)*4+j
    #pragma unroll
    for (int mf = 0; mf < 8; ++mf)
        #pragma unroll
        for (int j = 0; j < 4; ++j)
            lds_p[wv][mf * 16 + g * 4 + j][r] = acc[mf][j];
    __syncthreads();

    // reduce + gates: 512 threads = 128 batch x 4 j-cols
    {
        const int b = tid & 127, jj = tid >> 7;
        const int jout = jb + jj;
        float gs[4];
        #pragma unroll
        for (int qq = 0; qq < 4; ++qq) {
            const int col = qq * 4 + jj;
            float s = 0.f;
            #pragma unroll
            for (int w = 0; w < 8; ++w) s += lds_p[w][b][col];
            s += (LAYER == 0) ? extra[(long long)b * G4 + qq * H_DIM + jout]
                              : extra[qq * H_DIM + jout];
            gs[qq] = s;
        }
        const int cidx = jout * B_SZ + b;         // c transposed [j][b]
        float cn = sigf(gs[1]) * cst[cidx] + sigf(gs[0]) * tanhf(gs[2]);
        cst[cidx] = cn;
        float h = sigf(gs[3]) * tanhf(cn);
        // PK write: h as next A operand [128 rows=b][1024 k=j], NKT=32
        const long long di = (((long long)(b >> 4) * 32 + (jout >> 5)) * 64
                              + ((jout >> 3) & 3) * 16 + (b & 15)) * 8 + (jout & 7);
        unsigned short hh = f2bf(h);
        hohi[di] = hh;
        holo[di] = f2bf(h - bf2f(hh));
    }
}

// ---------- head: out[b,o] = h1[b,:] . w_out[o,:] + b_out[o] (PK h reads) ----
__global__ __launch_bounds__(64) void head_kernel(
    const unsigned short* __restrict__ hhi, const unsigned short* __restrict__ hlo,
    const float* __restrict__ w_out, const float* __restrict__ b_out,
    float* __restrict__ out)
{
    int o = blockIdx.x, b = blockIdx.y, lane = threadIdx.x;
    const float* wp = w_out + (long long)o * H_DIM;
    const long long rb = (long long)(b >> 4) * 32;
    const int rr = b & 15;
    float s = 0.f;
    for (int k = lane; k < H_DIM; k += 64) {
        long long di = ((rb + (k >> 5)) * 64 + ((k >> 3) & 3) * 16 + rr) * 8 + (k & 7);
        s += (bf2f(hhi[di]) + bf2f(hlo[di])) * wp[k];
    }
    #pragma unroll
    for (int off = 32; off; off >>= 1) s += __shfl_down(s, off);
    if (lane == 0) out[b * O_DIM + o] = s + b_out[o];
}

extern "C" void kernel_launch(void* const* d_in, const int* in_sizes, int n_in,
                              void* d_out, int out_size, void* d_ws, size_t ws_size,
                              hipStream_t stream)
{
    const float* input   = (const float*)d_in[0];
    const float* w_ih_l0 = (const float*)d_in[1];
    const float* w_hh_l0 = (const float*)d_in[2];
    const float* b_ih_l0 = (const float*)d_in[3];
    const float* b_hh_l0 = (const float*)d_in[4];
    const float* w_ih_l1 = (const float*)d_in[5];
    const float* w_hh_l1 = (const float*)d_in[6];
    const float* b_ih_l1 = (const float*)d_in[7];
    const float* b_hh_l1 = (const float*)d_in[8];
    const float* w_out   = (const float*)d_in[9];
    const float* b_out   = (const float*)d_in[10];
    float* out = (float*)d_out;

    char* base = (char*)d_ws;
    size_t off = 0;
    auto alloc = [&](size_t bytes) { char* p = base + off; off = (off + bytes + 255) & ~(size_t)255; return p; };
    unsigned short* wih0_hi = (unsigned short*)alloc(2097152 * 2);
    unsigned short* wih0_lo = (unsigned short*)alloc(2097152 * 2);
    unsigned short* whh0_hi = (unsigned short*)alloc(4194304 * 2);
    unsigned short* whh0_lo = (unsigned short*)alloc(4194304 * 2);
    unsigned short* wih1_hi = (unsigned short*)alloc(4194304 * 2);
    unsigned short* wih1_lo = (unsigned short*)alloc(4194304 * 2);
    unsigned short* whh1_hi = (unsigned short*)alloc(4194304 * 2);
    unsigned short* whh1_lo = (unsigned short*)alloc(4194304 * 2);
    unsigned short* xhi     = (unsigned short*)alloc(327680 * 2);
    unsigned short* xlo     = (unsigned short*)alloc(327680 * 2);
    float* xg0   = (float*)alloc((size_t)NSTEP * B_SZ * G4 * 4);
    float* bsum0 = (float*)alloc(G4 * 4);
    float* bsum1 = (float*)alloc(G4 * 4);
    float* c0    = (float*)alloc(B_SZ * H_DIM * 4);
    float* c1    = (float*)alloc(B_SZ * H_DIM * 4);
    unsigned short* h0hi[2], *h0lo[2], *h1hi[2], *h1lo[2];
    for (int i = 0; i < 2; ++i) {
        h0hi[i] = (unsigned short*)alloc(B_SZ * H_DIM * 2);
        h0lo[i] = (unsigned short*)alloc(B_SZ * H_DIM * 2);
        h1hi[i] = (unsigned short*)alloc(B_SZ * H_DIM * 2);
        h1lo[i] = (unsigned short*)alloc(B_SZ * H_DIM * 2);
    }

    init_misc<<<(B_SZ * H_DIM + 255) / 256, 256, 0, stream>>>(
        c0, c1, h0hi[0], h0lo[0], h1hi[0], h1lo[0],
        b_ih_l0, b_hh_l0, b_ih_l1, b_hh_l1, bsum0, bsum1);

    conv_pack<<<7328, 256, 0, stream>>>(
        w_ih_l0, w_hh_l0, w_ih_l1, w_hh_l1, input,
        wih0_hi, wih0_lo, whh0_hi, whh0_lo, wih1_hi, wih1_lo,
        whh1_hi, whh1_lo, xhi, xlo);

    gemm_in<<<dim3(G4 / 64, (NSTEP * B_SZ) / 64), 256, 0, stream>>>(
        xhi, xlo, wih0_hi, wih0_lo, bsum0, xg0);

    for (int t = 0; t < NSTEP; ++t) {
        int in = t & 1, o2 = 1 - in;
        lstm_step<0><<<H_DIM / 4, 512, 0, stream>>>(
            h0hi[in], h0lo[in], whh0_hi, whh0_lo,
            nullptr, nullptr, nullptr, nullptr,
            xg0 + (size_t)t * B_SZ * G4, c0, h0hi[o2], h0lo[o2]);
        lstm_step<1><<<H_DIM / 4, 512, 0, stream>>>(
            h0hi[o2], h0lo[o2], wih1_hi, wih1_lo,
            h1hi[in], h1lo[in], whh1_hi, whh1_lo,
            bsum1, c1, h1hi[o2], h1lo[o2]);
    }

    // t=4: out parity = 1
    head_kernel<<<dim3(O_DIM, B_SZ), 64, 0, stream>>>(
        h1hi[1], h1lo[1], w_out, b_out, out);
}